// Round 17
// baseline (77.559 us; speedup 1.0000x reference)
//
#include <hip/hip_runtime.h>
#include <hip/hip_cooperative_groups.h>
#include <math.h>

namespace cg = cooperative_groups;

#define C_ 128
#define N_ 16384

// ws layout (float offsets)
#define WS_Z    0                          // 8*128
#define WS_CTX  1024                       // 8*4*32*32
#define WS_A    164864                     // 8*128*128
#define WS_PCTX 295936                     // 512 slots * 4096 (t pre-combined)
#define WS_PZ   (WS_PCTX + 512*4096)       // 512 slots * 128
#define WS_END  (WS_PZ + 512*128)

typedef __attribute__((ext_vector_type(8))) short bf16x8;
typedef __attribute__((ext_vector_type(4))) float f32x4;
typedef __attribute__((ext_vector_type(4))) unsigned int u32x4;
typedef __attribute__((ext_vector_type(2))) unsigned int u32x2;

__device__ __forceinline__ unsigned int pkbf(float a, float b) {
  unsigned int r;
  asm("v_cvt_pk_bf16_f32 %0, %1, %2" : "=v"(r) : "v"(a), "v"(b));
  return r;
}

__device__ __forceinline__ bf16x8 make_frag(float4 u, float4 v) {
  u32x4 q = {pkbf(u.x, u.y), pkbf(u.z, u.w), pkbf(v.x, v.y), pkbf(v.z, v.w)};
  return *(bf16x8*)&q;
}

__device__ __forceinline__ bf16x8 lds_frag16(const unsigned short* p) {
  u32x4 q = *(const u32x4*)p;
  return *(bf16x8*)&q;
}

__device__ __forceinline__ void load4(const float* p, float* o) {
  float4 v = *(const float4*)p;
  o[0] = v.x; o[1] = v.y; o[2] = v.z; o[3] = v.w;
}

// xs tile addressing: [64 n-rows][136 u16 c-cols], stride 272 B.
// XOR byte bits 4-5 with row bits 4-5: reads unaffected, writes 8way->2way.
__device__ __forceinline__ void* xsa(void* base, int row, int col_bytes) {
  return (void*)((char*)base + row * 272 + (col_bytes ^ (((row >> 4) & 3) << 4)));
}

// ---------------------------------------------------------------------------
// FUSED (R12 base; one change: P3 st0/st1 x-loads hoisted before grid.syncs):
//   phase 0 = all phases with grid.sync (cooperative launch);
//   phase 1..4 = single phase (plain launch fallback).
//   P1  (512 blk): k1 — KV^T MFMA, exp, ctx partials, depth-1 reg prefetch.
//   P2a (128 blk): wide reduce partials -> WS_CTX, WS_Z.
//   P2b ( 32 blk): A[b] = Wout @ (cn @ Wq) reassociated.
//   P3  (512 blk): k3 — y = A @ x + bias (regular float4 stores; NT refuted
//                  R16: WRITE_SIZE +13MB from partial-line RMW).
// ---------------------------------------------------------------------------
__global__ __launch_bounds__(512, 2) void fused(const float* __restrict__ x,
                                                const float* __restrict__ wqkv,
                                                const float* __restrict__ wout,
                                                const float* __restrict__ bout,
                                                float* __restrict__ ws,
                                                float* __restrict__ y,
                                                int phase) {
  __shared__ __attribute__((aligned(16))) union {
    struct { unsigned short xs[64][136]; unsigned short ekv[2][128][72]; } p1; // 54.2 KB
    struct { float4 part[8][64]; } p2a;                                        // 8 KB
    struct { float cn[4][32][33]; float g[32][132]; float wst[32][132];
             float zsh[128]; } p2b;                                            // 50.2 KB
    struct { unsigned short xs2[2][64][136]; } p3;                             // 34.8 KB
  } sm;
  const int tid = threadIdx.x;
  const int bid = blockIdx.x;
  cg::grid_group grid = cg::this_grid();

  // P3 prologue data, loaded early (rides across grid.syncs)
  float p3va[4][4], p3pf[4][4];

  // ================= Phase 1: k1 =================
  if (phase == 0 || phase == 1) {
    const int j = bid & 63;               // n-chunk
    const int b = bid >> 6;
    const int wave = tid >> 6;
    const int l15  = tid & 15;
    const int l4   = (tid >> 4) & 3;
    const int h    = wave & 3;
    const int t    = wave >> 2;
    const int kvrow0 = h * 32 + t * 128;
    const float* xb = x + (size_t)b * ((size_t)C_ * N_);
    const int sn4 = tid & 15;
    const int scq = tid >> 4;

    bf16x8 wf[2][4];
    #pragma unroll
    for (int mi = 0; mi < 2; ++mi)
      #pragma unroll
      for (int ki = 0; ki < 4; ++ki) {
        const float* p = wqkv + (size_t)(128 + kvrow0 + mi * 16 + l15) * C_ + ki * 32 + l4 * 8;
        wf[mi][ki] = make_frag(*(const float4*)p, *(const float4*)(p + 4));
      }

    {
      float va[4][4];
      #pragma unroll
      for (int r = 0; r < 4; ++r)
        load4(xb + (size_t)(scq * 4 + r) * N_ + j * 256 + sn4 * 4, va[r]);
      #pragma unroll
      for (int i = 0; i < 4; ++i) {
        u32x2 w = {pkbf(va[0][i], va[1][i]), pkbf(va[2][i], va[3][i])};
        *(u32x2*)xsa(&sm.p1.xs[0][0], sn4 * 4 + i, scq * 8) = w;
      }
    }
    __syncthreads();

    const f32x4 z4 = {0.f, 0.f, 0.f, 0.f};
    f32x4 ctxacc[2][2];
    #pragma unroll
    for (int i = 0; i < 2; ++i)
      #pragma unroll
      for (int jj = 0; jj < 2; ++jj) ctxacc[i][jj] = z4;
    float zacc[2] = {0.f, 0.f};

    for (int st = 0; st < 4; ++st) {
      float pf[4][4];
      if (st < 3) {
        const int nbn = j * 256 + (st + 1) * 64;
        #pragma unroll
        for (int r = 0; r < 4; ++r)
          load4(xb + (size_t)(scq * 4 + r) * N_ + nbn + sn4 * 4, pf[r]);
      }

      #pragma unroll
      for (int half = 0; half < 2; ++half) {
        f32x4 acc[2][2];
        #pragma unroll
        for (int a = 0; a < 2; ++a)
          #pragma unroll
          for (int m = 0; m < 2; ++m) acc[a][m] = z4;
        #pragma unroll
        for (int ki = 0; ki < 4; ++ki) {
          bf16x8 bfr[2];
          #pragma unroll
          for (int ni2 = 0; ni2 < 2; ++ni2)
            bfr[ni2] = lds_frag16((const unsigned short*)
                xsa(&sm.p1.xs[0][0], half * 32 + ni2 * 16 + l15, ki * 64 + l4 * 16));
          __builtin_amdgcn_s_setprio(1);
          #pragma unroll
          for (int ni2 = 0; ni2 < 2; ++ni2)
            #pragma unroll
            for (int mi = 0; mi < 2; ++mi)
              acc[ni2][mi] = __builtin_amdgcn_mfma_f32_16x16x32_bf16(
                  bfr[ni2], wf[mi][ki], acc[ni2][mi], 0, 0, 0);
          __builtin_amdgcn_s_setprio(0);
        }
        #pragma unroll
        for (int ni2 = 0; ni2 < 2; ++ni2)
          #pragma unroll
          for (int mi = 0; mi < 2; ++mi) {
            float e0, e1, e2, e3;
            if (t == 0) {
              e0 = __expf(acc[ni2][mi][0]); e1 = __expf(acc[ni2][mi][1]);
              e2 = __expf(acc[ni2][mi][2]); e3 = __expf(acc[ni2][mi][3]);
              zacc[mi] += (e0 + e1) + (e2 + e3);
            } else {
              e0 = acc[ni2][mi][0]; e1 = acc[ni2][mi][1];
              e2 = acc[ni2][mi][2]; e3 = acc[ni2][mi][3];
            }
            u32x2 w = {pkbf(e0, e1), pkbf(e2, e3)};
            *(u32x2*)&sm.p1.ekv[t][h * 32 + mi * 16 + l15][(half * 2 + ni2) * 16 + l4 * 4] = w;
          }
      }
      __syncthreads();

      {
        bf16x8 af2[2], bv2[2];
        #pragma unroll
        for (int m2 = 0; m2 < 2; ++m2)
          af2[m2] = lds_frag16(&sm.p1.ekv[0][h * 32 + m2 * 16 + l15][t * 32 + l4 * 8]);
        #pragma unroll
        for (int n2 = 0; n2 < 2; ++n2)
          bv2[n2] = lds_frag16(&sm.p1.ekv[1][h * 32 + n2 * 16 + l15][t * 32 + l4 * 8]);
        __builtin_amdgcn_s_setprio(1);
        #pragma unroll
        for (int m2 = 0; m2 < 2; ++m2)
          #pragma unroll
          for (int n2 = 0; n2 < 2; ++n2)
            ctxacc[m2][n2] = __builtin_amdgcn_mfma_f32_16x16x32_bf16(
                af2[m2], bv2[n2], ctxacc[m2][n2], 0, 0, 0);
        __builtin_amdgcn_s_setprio(0);
      }

      if (st < 3) {
        #pragma unroll
        for (int i = 0; i < 4; ++i) {
          u32x2 w = {pkbf(pf[0][i], pf[1][i]), pkbf(pf[2][i], pf[3][i])};
          *(u32x2*)xsa(&sm.p1.xs[0][0], sn4 * 4 + i, scq * 8) = w;
        }
      }
      __syncthreads();
    }

    // epilogue: in-block t-combine, one partial slot per (b,j)
    {
      float* csh = (float*)&sm.p1.ekv[0][0][0];
      if (t == 1) {
        #pragma unroll
        for (int m2 = 0; m2 < 2; ++m2)
          #pragma unroll
          for (int n2 = 0; n2 < 2; ++n2)
            #pragma unroll
            for (int r = 0; r < 4; ++r)
              csh[h * 1152 + (m2 * 16 + l4 * 4 + r) * 36 + n2 * 16 + l15] =
                  ctxacc[m2][n2][r];
      }
      __syncthreads();
      if (t == 0) {
        #pragma unroll
        for (int m2 = 0; m2 < 2; ++m2)
          #pragma unroll
          for (int n2 = 0; n2 < 2; ++n2)
            #pragma unroll
            for (int r = 0; r < 4; ++r)
              ctxacc[m2][n2][r] +=
                  csh[h * 1152 + (m2 * 16 + l4 * 4 + r) * 36 + n2 * 16 + l15];
        float* ps = ws + WS_PCTX + (size_t)(b * 64 + j) * 4096 + h * 1024;
        #pragma unroll
        for (int m2 = 0; m2 < 2; ++m2)
          #pragma unroll
          for (int n2 = 0; n2 < 2; ++n2)
            #pragma unroll
            for (int r = 0; r < 4; ++r)
              ps[(m2 * 16 + l4 * 4 + r) * 32 + n2 * 16 + l15] = ctxacc[m2][n2][r];
        #pragma unroll
        for (int mi = 0; mi < 2; ++mi) {
          float z = zacc[mi];
          z += __shfl_xor(z, 16);
          z += __shfl_xor(z, 32);
          if ((tid & 48) == 0)
            ws[WS_PZ + (size_t)(b * 64 + j) * 128 + h * 32 + mi * 16 + l15] = z;
        }
      }
    }
  }

  // hoisted P3 prologue loads: same (b,j) x region (L2-hot from P1);
  // registers ride across the grid.syncs, hiding P3's serial load-wait.
  if (phase == 0) {
    const int j = bid & 63;
    const int b = bid >> 6;
    const float* xb = x + (size_t)b * ((size_t)C_ * N_);
    const int sn4 = tid & 15;
    const int scq = tid >> 4;
    #pragma unroll
    for (int r = 0; r < 4; ++r)
      load4(xb + (size_t)(scq * 4 + r) * N_ + j * 256 + sn4 * 4, p3va[r]);
    #pragma unroll
    for (int r = 0; r < 4; ++r)
      load4(xb + (size_t)(scq * 4 + r) * N_ + j * 256 + 64 + sn4 * 4, p3pf[r]);
  }

  if (phase == 0) grid.sync();

  // ================= Phase 2a: wide reduce =================
  if ((phase == 0 || phase == 2) && bid < 128) {
    const int eq = bid & 3, h = (bid >> 2) & 3, b = bid >> 4;
    const int f4 = tid & 63, p = tid >> 6;
    const float* base = ws + WS_PCTX + (size_t)(b * 64) * 4096
                           + h * 1024 + eq * 256 + f4 * 4;
    float4 s = {0.f, 0.f, 0.f, 0.f};
    #pragma unroll
    for (int q = 0; q < 8; ++q) {
      float4 v = *(const float4*)(base + (size_t)(p * 8 + q) * 4096);
      s.x += v.x; s.y += v.y; s.z += v.z; s.w += v.w;
    }
    sm.p2a.part[p][f4] = s;
    if (eq == 0 && tid < 32) {
      const float* pz = ws + WS_PZ + (size_t)(b * 64) * 128 + h * 32 + tid;
      float z = 0.f;
      #pragma unroll 8
      for (int q = 0; q < 64; ++q) z += pz[(size_t)q * 128];
      ws[WS_Z + b * 128 + h * 32 + tid] = z;
    }
    __syncthreads();
    if (tid < 64) {
      float4 o = {0.f, 0.f, 0.f, 0.f};
      #pragma unroll
      for (int p2 = 0; p2 < 8; ++p2) {
        float4 a = sm.p2a.part[p2][tid];
        o.x += a.x; o.y += a.y; o.z += a.z; o.w += a.w;
      }
      *(float4*)(ws + WS_CTX + (size_t)(b * 4 + h) * 1024 + eq * 256 + tid * 4) = o;
    }
  }
  if (phase == 0) grid.sync();

  // ================= Phase 2b: A = Wout @ (cn @ Wq) =================
  if ((phase == 0 || phase == 3) && bid < 32) {
    const int oq = bid & 3, b = bid >> 2;
    if (tid < 128) sm.p2b.zsh[tid] = ws[WS_Z + b * 128 + tid];
    __syncthreads();
    {
      const int idx = tid * 8;
      const int h = idx >> 10, d = (idx >> 5) & 31, e0 = idx & 31;
      const float zi = 1.f / sm.p2b.zsh[h * 32 + d];
      const float* p = ws + WS_CTX + (size_t)b * 4096 + idx;
      #pragma unroll
      for (int i = 0; i < 8; ++i) sm.p2b.cn[h][d][e0 + i] = p[i] * zi;
    }
    {
      const int r = tid >> 4, f = (tid & 15) * 8;
      *(float4*)&sm.p2b.wst[r][f]     = *(const float4*)(wout + (oq * 32 + r) * 128 + f);
      *(float4*)&sm.p2b.wst[r][f + 4] = *(const float4*)(wout + (oq * 32 + r) * 128 + f + 4);
    }
    __syncthreads();
    const int o = tid >> 4, q8 = (tid & 15) * 8;
    float gacc[8];
    #pragma unroll
    for (int i = 0; i < 8; ++i) {
      const int hd = q8 + i, h = hd >> 5, d = hd & 31;
      float s = 0.f;
      for (int e = 0; e < 32; ++e)
        s = fmaf(sm.p2b.wst[o][h * 32 + e], sm.p2b.cn[h][d][e], s);
      gacc[i] = s;
    }
    #pragma unroll
    for (int i = 0; i < 8; ++i) sm.p2b.g[o][q8 + i] = gacc[i];
    float s3[8];
    #pragma unroll
    for (int jj = 0; jj < 8; ++jj) s3[jj] = 0.f;
    for (int h = 0; h < 4; ++h) {
      __syncthreads();
      const int r = tid >> 4, f = (tid & 15) * 8;
      *(float4*)&sm.p2b.wst[r][f]     = *(const float4*)(wqkv + (h * 32 + r) * 128 + f);
      *(float4*)&sm.p2b.wst[r][f + 4] = *(const float4*)(wqkv + (h * 32 + r) * 128 + f + 4);
      __syncthreads();
      for (int d = 0; d < 32; ++d) {
        const float gg = sm.p2b.g[o][h * 32 + d];
        #pragma unroll
        for (int jj = 0; jj < 8; ++jj)
          s3[jj] = fmaf(gg, sm.p2b.wst[d][q8 + jj], s3[jj]);
      }
    }
    float* A = ws + WS_A + ((size_t)b * 128 + oq * 32 + o) * 128;
    #pragma unroll
    for (int jj = 0; jj < 8; ++jj) A[q8 + jj] = s3[jj];
  }
  if (phase == 0) grid.sync();

  // ================= Phase 3: k3 =================
  if (phase == 0 || phase == 4) {
    const int j = bid & 63;
    const int b = bid >> 6;
    const int wave = tid >> 6;
    const int l15  = tid & 15;
    const int l4   = (tid >> 4) & 3;
    const int n0   = j * 256;
    const float* xb = x + (size_t)b * ((size_t)C_ * N_);
    const float* A  = ws + WS_A + (size_t)b * 128 * 128;
    const int sn4 = tid & 15;
    const int scq = tid >> 4;

    if (phase == 4) {   // fallback: load prologue data now
      #pragma unroll
      for (int r = 0; r < 4; ++r)
        load4(xb + (size_t)(scq * 4 + r) * N_ + n0 + sn4 * 4, p3va[r]);
      #pragma unroll
      for (int r = 0; r < 4; ++r)
        load4(xb + (size_t)(scq * 4 + r) * N_ + n0 + 64 + sn4 * 4, p3pf[r]);
    }

    bf16x8 af[4];
    #pragma unroll
    for (int ki = 0; ki < 4; ++ki) {
      const float* p = A + (size_t)(wave * 16 + l15) * 128 + ki * 32 + l4 * 8;
      af[ki] = make_frag(*(const float4*)p, *(const float4*)(p + 4));
    }
    const float bias = bout[wave * 16 + l15];

    // stage subtile 0 from pre-loaded registers
    #pragma unroll
    for (int i = 0; i < 4; ++i) {
      u32x2 w = {pkbf(p3va[0][i], p3va[1][i]), pkbf(p3va[2][i], p3va[3][i])};
      *(u32x2*)xsa(&sm.p3.xs2[0][0][0], sn4 * 4 + i, scq * 8) = w;
    }
    __syncthreads();

    const f32x4 z4 = {0.f, 0.f, 0.f, 0.f};
    float* yb = y + (size_t)b * ((size_t)128 * N_);

    #pragma unroll
    for (int st = 0; st < 4; ++st) {
      const int nb = n0 + st * 64;
      float pf[4][4];
      if (st == 0) {
        #pragma unroll
        for (int r = 0; r < 4; ++r)
          #pragma unroll
          for (int i = 0; i < 4; ++i) pf[r][i] = p3pf[r][i];
      } else if (st < 3) {
        #pragma unroll
        for (int r = 0; r < 4; ++r)
          load4(xb + (size_t)(scq * 4 + r) * N_ + nb + 64 + sn4 * 4, pf[r]);
      }

      f32x4 acc[4];
      #pragma unroll
      for (int ni = 0; ni < 4; ++ni) acc[ni] = z4;
      #pragma unroll
      for (int ki = 0; ki < 4; ++ki) {
        bf16x8 bfr[4];
        #pragma unroll
        for (int ni = 0; ni < 4; ++ni)
          bfr[ni] = lds_frag16((const unsigned short*)
              xsa(&sm.p3.xs2[st & 1][0][0], ni * 16 + l15, ki * 64 + l4 * 16));
        #pragma unroll
        for (int ni = 0; ni < 4; ++ni)
          acc[ni] = __builtin_amdgcn_mfma_f32_16x16x32_bf16(
              bfr[ni], af[ki], acc[ni], 0, 0, 0);
      }

      if (st < 3) {
        #pragma unroll
        for (int i = 0; i < 4; ++i) {
          u32x2 w = {pkbf(pf[0][i], pf[1][i]), pkbf(pf[2][i], pf[3][i])};
          *(u32x2*)xsa(&sm.p3.xs2[(st + 1) & 1][0][0], sn4 * 4 + i, scq * 8) = w;
        }
      }

      #pragma unroll
      for (int ni = 0; ni < 4; ++ni) {
        float4 o;
        o.x = acc[ni][0] + bias;
        o.y = acc[ni][1] + bias;
        o.z = acc[ni][2] + bias;
        o.w = acc[ni][3] + bias;
        *(float4*)(yb + (size_t)(wave * 16 + l15) * N_ + nb + ni * 16 + l4 * 4) = o;
      }

      if (st < 3) __syncthreads();
    }
  }
}

extern "C" void kernel_launch(void* const* d_in, const int* in_sizes, int n_in,
                              void* d_out, int out_size, void* d_ws, size_t ws_size,
                              hipStream_t stream) {
  const float* x     = (const float*)d_in[0];
  const float* w_qkv = (const float*)d_in[1];
  const float* w_out = (const float*)d_in[2];
  const float* b_out = (const float*)d_in[3];
  float* y  = (float*)d_out;
  float* ws = (float*)d_ws;

  int maxb = 0;
  hipError_t oe = hipOccupancyMaxActiveBlocksPerMultiprocessor(&maxb, fused, 512, 0);
  const bool coop = (oe == hipSuccess && maxb >= 2 &&
                     ws_size >= (size_t)WS_END * sizeof(float));

  if (coop) {
    int ph = 0;
    void* args[] = {(void*)&x, (void*)&w_qkv, (void*)&w_out, (void*)&b_out,
                    (void*)&ws, (void*)&y, (void*)&ph};
    hipError_t e = hipLaunchCooperativeKernel(reinterpret_cast<void*>(fused),
                                              dim3(512), dim3(512), args, 0, stream);
    if (e == hipSuccess) return;
  }
  fused<<<512, 512, 0, stream>>>(x, w_qkv, w_out, b_out, ws, y, 1);
  fused<<<128, 512, 0, stream>>>(x, w_qkv, w_out, b_out, ws, y, 2);
  fused<<< 32, 512, 0, stream>>>(x, w_qkv, w_out, b_out, ws, y, 3);
  fused<<<512, 512, 0, stream>>>(x, w_qkv, w_out, b_out, ws, y, 4);
}

// Round 18
// 71.689 us; speedup vs baseline: 1.0819x; 1.0819x over previous
//
#include <hip/hip_runtime.h>
#include <hip/hip_cooperative_groups.h>
#include <math.h>

namespace cg = cooperative_groups;

#define C_ 128
#define N_ 16384

// ws layout (float offsets)
#define WS_Z    0                          // 8*128
#define WS_CTX  1024                       // 8*4*32*32
#define WS_A    164864                     // 8*128*128
#define WS_PCTX 295936                     // 512 slots * 4096 (t pre-combined)
#define WS_PZ   (WS_PCTX + 512*4096)       // 512 slots * 128
#define WS_END  (WS_PZ + 512*128)

typedef __attribute__((ext_vector_type(8))) short bf16x8;
typedef __attribute__((ext_vector_type(4))) float f32x4;
typedef __attribute__((ext_vector_type(4))) unsigned int u32x4;
typedef __attribute__((ext_vector_type(2))) unsigned int u32x2;

__device__ __forceinline__ unsigned int pkbf(float a, float b) {
  unsigned int r;
  asm("v_cvt_pk_bf16_f32 %0, %1, %2" : "=v"(r) : "v"(a), "v"(b));
  return r;
}

__device__ __forceinline__ bf16x8 make_frag(float4 u, float4 v) {
  u32x4 q = {pkbf(u.x, u.y), pkbf(u.z, u.w), pkbf(v.x, v.y), pkbf(v.z, v.w)};
  return *(bf16x8*)&q;
}

__device__ __forceinline__ bf16x8 lds_frag16(const unsigned short* p) {
  u32x4 q = *(const u32x4*)p;
  return *(bf16x8*)&q;
}

__device__ __forceinline__ void load4(const float* p, float* o) {
  float4 v = *(const float4*)p;
  o[0] = v.x; o[1] = v.y; o[2] = v.z; o[3] = v.w;
}

// xs tile addressing: [64 n-rows][136 u16 c-cols], stride 272 B.
// XOR byte bits 4-5 with row bits 4-5: reads unaffected, writes 8way->2way.
__device__ __forceinline__ void* xsa(void* base, int row, int col_bytes) {
  return (void*)((char*)base + row * 272 + (col_bytes ^ (((row >> 4) & 3) << 4)));
}

// ---------------------------------------------------------------------------
// FUSED (byte-exact R12 rebank — best measured config, 71.87 us):
//   phase 0 = all phases with grid.sync (cooperative launch);
//   phase 1..4 = single phase (plain launch fallback).
//   P1  (512 blk): k1 — KV^T MFMA, exp, ctx partials, depth-1 reg prefetch.
//   P2a (128 blk): wide reduce partials -> WS_CTX, WS_Z.
//   P2b ( 32 blk): A[b] = Wout @ (cn @ Wq) reassociated.
//   P3  (512 blk): k3 — y = A @ x + bias.
// Coop box (confirmed R13/14/17): VGPR <= ~128, LDS <= 80 KB, grid = 512.
// ---------------------------------------------------------------------------
__global__ __launch_bounds__(512, 2) void fused(const float* __restrict__ x,
                                                const float* __restrict__ wqkv,
                                                const float* __restrict__ wout,
                                                const float* __restrict__ bout,
                                                float* __restrict__ ws,
                                                float* __restrict__ y,
                                                int phase) {
  __shared__ __attribute__((aligned(16))) union {
    struct { unsigned short xs[64][136]; unsigned short ekv[2][128][72]; } p1; // 54.2 KB
    struct { float4 part[8][64]; } p2a;                                        // 8 KB
    struct { float cn[4][32][33]; float g[32][132]; float wst[32][132];
             float zsh[128]; } p2b;                                            // 50.2 KB
    struct { unsigned short xs2[2][64][136]; } p3;                             // 34.8 KB
  } sm;
  const int tid = threadIdx.x;
  const int bid = blockIdx.x;
  cg::grid_group grid = cg::this_grid();

  // ================= Phase 1: k1 =================
  if (phase == 0 || phase == 1) {
    const int j = bid & 63;               // n-chunk
    const int b = bid >> 6;
    const int wave = tid >> 6;
    const int l15  = tid & 15;
    const int l4   = (tid >> 4) & 3;
    const int h    = wave & 3;
    const int t    = wave >> 2;
    const int kvrow0 = h * 32 + t * 128;
    const float* xb = x + (size_t)b * ((size_t)C_ * N_);
    const int sn4 = tid & 15;
    const int scq = tid >> 4;

    bf16x8 wf[2][4];
    #pragma unroll
    for (int mi = 0; mi < 2; ++mi)
      #pragma unroll
      for (int ki = 0; ki < 4; ++ki) {
        const float* p = wqkv + (size_t)(128 + kvrow0 + mi * 16 + l15) * C_ + ki * 32 + l4 * 8;
        wf[mi][ki] = make_frag(*(const float4*)p, *(const float4*)(p + 4));
      }

    {
      float va[4][4];
      #pragma unroll
      for (int r = 0; r < 4; ++r)
        load4(xb + (size_t)(scq * 4 + r) * N_ + j * 256 + sn4 * 4, va[r]);
      #pragma unroll
      for (int i = 0; i < 4; ++i) {
        u32x2 w = {pkbf(va[0][i], va[1][i]), pkbf(va[2][i], va[3][i])};
        *(u32x2*)xsa(&sm.p1.xs[0][0], sn4 * 4 + i, scq * 8) = w;
      }
    }
    __syncthreads();

    const f32x4 z4 = {0.f, 0.f, 0.f, 0.f};
    f32x4 ctxacc[2][2];
    #pragma unroll
    for (int i = 0; i < 2; ++i)
      #pragma unroll
      for (int jj = 0; jj < 2; ++jj) ctxacc[i][jj] = z4;
    float zacc[2] = {0.f, 0.f};

    for (int st = 0; st < 4; ++st) {
      float pf[4][4];
      if (st < 3) {
        const int nbn = j * 256 + (st + 1) * 64;
        #pragma unroll
        for (int r = 0; r < 4; ++r)
          load4(xb + (size_t)(scq * 4 + r) * N_ + nbn + sn4 * 4, pf[r]);
      }

      #pragma unroll
      for (int half = 0; half < 2; ++half) {
        f32x4 acc[2][2];
        #pragma unroll
        for (int a = 0; a < 2; ++a)
          #pragma unroll
          for (int m = 0; m < 2; ++m) acc[a][m] = z4;
        #pragma unroll
        for (int ki = 0; ki < 4; ++ki) {
          bf16x8 bfr[2];
          #pragma unroll
          for (int ni2 = 0; ni2 < 2; ++ni2)
            bfr[ni2] = lds_frag16((const unsigned short*)
                xsa(&sm.p1.xs[0][0], half * 32 + ni2 * 16 + l15, ki * 64 + l4 * 16));
          __builtin_amdgcn_s_setprio(1);
          #pragma unroll
          for (int ni2 = 0; ni2 < 2; ++ni2)
            #pragma unroll
            for (int mi = 0; mi < 2; ++mi)
              acc[ni2][mi] = __builtin_amdgcn_mfma_f32_16x16x32_bf16(
                  bfr[ni2], wf[mi][ki], acc[ni2][mi], 0, 0, 0);
          __builtin_amdgcn_s_setprio(0);
        }
        #pragma unroll
        for (int ni2 = 0; ni2 < 2; ++ni2)
          #pragma unroll
          for (int mi = 0; mi < 2; ++mi) {
            float e0, e1, e2, e3;
            if (t == 0) {
              e0 = __expf(acc[ni2][mi][0]); e1 = __expf(acc[ni2][mi][1]);
              e2 = __expf(acc[ni2][mi][2]); e3 = __expf(acc[ni2][mi][3]);
              zacc[mi] += (e0 + e1) + (e2 + e3);
            } else {
              e0 = acc[ni2][mi][0]; e1 = acc[ni2][mi][1];
              e2 = acc[ni2][mi][2]; e3 = acc[ni2][mi][3];
            }
            u32x2 w = {pkbf(e0, e1), pkbf(e2, e3)};
            *(u32x2*)&sm.p1.ekv[t][h * 32 + mi * 16 + l15][(half * 2 + ni2) * 16 + l4 * 4] = w;
          }
      }
      __syncthreads();

      {
        bf16x8 af2[2], bv2[2];
        #pragma unroll
        for (int m2 = 0; m2 < 2; ++m2)
          af2[m2] = lds_frag16(&sm.p1.ekv[0][h * 32 + m2 * 16 + l15][t * 32 + l4 * 8]);
        #pragma unroll
        for (int n2 = 0; n2 < 2; ++n2)
          bv2[n2] = lds_frag16(&sm.p1.ekv[1][h * 32 + n2 * 16 + l15][t * 32 + l4 * 8]);
        __builtin_amdgcn_s_setprio(1);
        #pragma unroll
        for (int m2 = 0; m2 < 2; ++m2)
          #pragma unroll
          for (int n2 = 0; n2 < 2; ++n2)
            ctxacc[m2][n2] = __builtin_amdgcn_mfma_f32_16x16x32_bf16(
                af2[m2], bv2[n2], ctxacc[m2][n2], 0, 0, 0);
        __builtin_amdgcn_s_setprio(0);
      }

      if (st < 3) {
        #pragma unroll
        for (int i = 0; i < 4; ++i) {
          u32x2 w = {pkbf(pf[0][i], pf[1][i]), pkbf(pf[2][i], pf[3][i])};
          *(u32x2*)xsa(&sm.p1.xs[0][0], sn4 * 4 + i, scq * 8) = w;
        }
      }
      __syncthreads();
    }

    // epilogue: in-block t-combine, one partial slot per (b,j)
    {
      float* csh = (float*)&sm.p1.ekv[0][0][0];
      if (t == 1) {
        #pragma unroll
        for (int m2 = 0; m2 < 2; ++m2)
          #pragma unroll
          for (int n2 = 0; n2 < 2; ++n2)
            #pragma unroll
            for (int r = 0; r < 4; ++r)
              csh[h * 1152 + (m2 * 16 + l4 * 4 + r) * 36 + n2 * 16 + l15] =
                  ctxacc[m2][n2][r];
      }
      __syncthreads();
      if (t == 0) {
        #pragma unroll
        for (int m2 = 0; m2 < 2; ++m2)
          #pragma unroll
          for (int n2 = 0; n2 < 2; ++n2)
            #pragma unroll
            for (int r = 0; r < 4; ++r)
              ctxacc[m2][n2][r] +=
                  csh[h * 1152 + (m2 * 16 + l4 * 4 + r) * 36 + n2 * 16 + l15];
        float* ps = ws + WS_PCTX + (size_t)(b * 64 + j) * 4096 + h * 1024;
        #pragma unroll
        for (int m2 = 0; m2 < 2; ++m2)
          #pragma unroll
          for (int n2 = 0; n2 < 2; ++n2)
            #pragma unroll
            for (int r = 0; r < 4; ++r)
              ps[(m2 * 16 + l4 * 4 + r) * 32 + n2 * 16 + l15] = ctxacc[m2][n2][r];
        #pragma unroll
        for (int mi = 0; mi < 2; ++mi) {
          float z = zacc[mi];
          z += __shfl_xor(z, 16);
          z += __shfl_xor(z, 32);
          if ((tid & 48) == 0)
            ws[WS_PZ + (size_t)(b * 64 + j) * 128 + h * 32 + mi * 16 + l15] = z;
        }
      }
    }
  }
  if (phase == 0) grid.sync();

  // ================= Phase 2a: wide reduce =================
  if ((phase == 0 || phase == 2) && bid < 128) {
    const int eq = bid & 3, h = (bid >> 2) & 3, b = bid >> 4;
    const int f4 = tid & 63, p = tid >> 6;
    const float* base = ws + WS_PCTX + (size_t)(b * 64) * 4096
                           + h * 1024 + eq * 256 + f4 * 4;
    float4 s = {0.f, 0.f, 0.f, 0.f};
    #pragma unroll
    for (int q = 0; q < 8; ++q) {
      float4 v = *(const float4*)(base + (size_t)(p * 8 + q) * 4096);
      s.x += v.x; s.y += v.y; s.z += v.z; s.w += v.w;
    }
    sm.p2a.part[p][f4] = s;
    if (eq == 0 && tid < 32) {
      const float* pz = ws + WS_PZ + (size_t)(b * 64) * 128 + h * 32 + tid;
      float z = 0.f;
      #pragma unroll 8
      for (int q = 0; q < 64; ++q) z += pz[(size_t)q * 128];
      ws[WS_Z + b * 128 + h * 32 + tid] = z;
    }
    __syncthreads();
    if (tid < 64) {
      float4 o = {0.f, 0.f, 0.f, 0.f};
      #pragma unroll
      for (int p2 = 0; p2 < 8; ++p2) {
        float4 a = sm.p2a.part[p2][tid];
        o.x += a.x; o.y += a.y; o.z += a.z; o.w += a.w;
      }
      *(float4*)(ws + WS_CTX + (size_t)(b * 4 + h) * 1024 + eq * 256 + tid * 4) = o;
    }
  }
  if (phase == 0) grid.sync();

  // ================= Phase 2b: A = Wout @ (cn @ Wq) =================
  if ((phase == 0 || phase == 3) && bid < 32) {
    const int oq = bid & 3, b = bid >> 2;
    if (tid < 128) sm.p2b.zsh[tid] = ws[WS_Z + b * 128 + tid];
    __syncthreads();
    {
      const int idx = tid * 8;
      const int h = idx >> 10, d = (idx >> 5) & 31, e0 = idx & 31;
      const float zi = 1.f / sm.p2b.zsh[h * 32 + d];
      const float* p = ws + WS_CTX + (size_t)b * 4096 + idx;
      #pragma unroll
      for (int i = 0; i < 8; ++i) sm.p2b.cn[h][d][e0 + i] = p[i] * zi;
    }
    {
      const int r = tid >> 4, f = (tid & 15) * 8;
      *(float4*)&sm.p2b.wst[r][f]     = *(const float4*)(wout + (oq * 32 + r) * 128 + f);
      *(float4*)&sm.p2b.wst[r][f + 4] = *(const float4*)(wout + (oq * 32 + r) * 128 + f + 4);
    }
    __syncthreads();
    const int o = tid >> 4, q8 = (tid & 15) * 8;
    float gacc[8];
    #pragma unroll
    for (int i = 0; i < 8; ++i) {
      const int hd = q8 + i, h = hd >> 5, d = hd & 31;
      float s = 0.f;
      for (int e = 0; e < 32; ++e)
        s = fmaf(sm.p2b.wst[o][h * 32 + e], sm.p2b.cn[h][d][e], s);
      gacc[i] = s;
    }
    #pragma unroll
    for (int i = 0; i < 8; ++i) sm.p2b.g[o][q8 + i] = gacc[i];
    float s3[8];
    #pragma unroll
    for (int jj = 0; jj < 8; ++jj) s3[jj] = 0.f;
    for (int h = 0; h < 4; ++h) {
      __syncthreads();
      const int r = tid >> 4, f = (tid & 15) * 8;
      *(float4*)&sm.p2b.wst[r][f]     = *(const float4*)(wqkv + (h * 32 + r) * 128 + f);
      *(float4*)&sm.p2b.wst[r][f + 4] = *(const float4*)(wqkv + (h * 32 + r) * 128 + f + 4);
      __syncthreads();
      for (int d = 0; d < 32; ++d) {
        const float gg = sm.p2b.g[o][h * 32 + d];
        #pragma unroll
        for (int jj = 0; jj < 8; ++jj)
          s3[jj] = fmaf(gg, sm.p2b.wst[d][q8 + jj], s3[jj]);
      }
    }
    float* A = ws + WS_A + ((size_t)b * 128 + oq * 32 + o) * 128;
    #pragma unroll
    for (int jj = 0; jj < 8; ++jj) A[q8 + jj] = s3[jj];
  }
  if (phase == 0) grid.sync();

  // ================= Phase 3: k3 =================
  if (phase == 0 || phase == 4) {
    const int j = bid & 63;
    const int b = bid >> 6;
    const int wave = tid >> 6;
    const int l15  = tid & 15;
    const int l4   = (tid >> 4) & 3;
    const int n0   = j * 256;
    const float* xb = x + (size_t)b * ((size_t)C_ * N_);
    const float* A  = ws + WS_A + (size_t)b * 128 * 128;
    const int sn4 = tid & 15;
    const int scq = tid >> 4;

    bf16x8 af[4];
    #pragma unroll
    for (int ki = 0; ki < 4; ++ki) {
      const float* p = A + (size_t)(wave * 16 + l15) * 128 + ki * 32 + l4 * 8;
      af[ki] = make_frag(*(const float4*)p, *(const float4*)(p + 4));
    }
    const float bias = bout[wave * 16 + l15];

    {
      float va[4][4];
      #pragma unroll
      for (int r = 0; r < 4; ++r)
        load4(xb + (size_t)(scq * 4 + r) * N_ + n0 + sn4 * 4, va[r]);
      #pragma unroll
      for (int i = 0; i < 4; ++i) {
        u32x2 w = {pkbf(va[0][i], va[1][i]), pkbf(va[2][i], va[3][i])};
        *(u32x2*)xsa(&sm.p3.xs2[0][0][0], sn4 * 4 + i, scq * 8) = w;
      }
    }
    __syncthreads();

    const f32x4 z4 = {0.f, 0.f, 0.f, 0.f};
    float* yb = y + (size_t)b * ((size_t)128 * N_);

    #pragma unroll
    for (int st = 0; st < 4; ++st) {
      const int nb = n0 + st * 64;
      float pf[4][4];
      if (st < 3) {
        #pragma unroll
        for (int r = 0; r < 4; ++r)
          load4(xb + (size_t)(scq * 4 + r) * N_ + nb + 64 + sn4 * 4, pf[r]);
      }

      f32x4 acc[4];
      #pragma unroll
      for (int ni = 0; ni < 4; ++ni) acc[ni] = z4;
      #pragma unroll
      for (int ki = 0; ki < 4; ++ki) {
        bf16x8 bfr[4];
        #pragma unroll
        for (int ni = 0; ni < 4; ++ni)
          bfr[ni] = lds_frag16((const unsigned short*)
              xsa(&sm.p3.xs2[st & 1][0][0], ni * 16 + l15, ki * 64 + l4 * 16));
        #pragma unroll
        for (int ni = 0; ni < 4; ++ni)
          acc[ni] = __builtin_amdgcn_mfma_f32_16x16x32_bf16(
              bfr[ni], af[ki], acc[ni], 0, 0, 0);
      }

      if (st < 3) {
        #pragma unroll
        for (int i = 0; i < 4; ++i) {
          u32x2 w = {pkbf(pf[0][i], pf[1][i]), pkbf(pf[2][i], pf[3][i])};
          *(u32x2*)xsa(&sm.p3.xs2[(st + 1) & 1][0][0], sn4 * 4 + i, scq * 8) = w;
        }
      }

      #pragma unroll
      for (int ni = 0; ni < 4; ++ni) {
        float4 o;
        o.x = acc[ni][0] + bias;
        o.y = acc[ni][1] + bias;
        o.z = acc[ni][2] + bias;
        o.w = acc[ni][3] + bias;
        *(float4*)(yb + (size_t)(wave * 16 + l15) * N_ + nb + ni * 16 + l4 * 4) = o;
      }

      if (st < 3) __syncthreads();
    }
  }
}

extern "C" void kernel_launch(void* const* d_in, const int* in_sizes, int n_in,
                              void* d_out, int out_size, void* d_ws, size_t ws_size,
                              hipStream_t stream) {
  const float* x     = (const float*)d_in[0];
  const float* w_qkv = (const float*)d_in[1];
  const float* w_out = (const float*)d_in[2];
  const float* b_out = (const float*)d_in[3];
  float* y  = (float*)d_out;
  float* ws = (float*)d_ws;

  int maxb = 0;
  hipError_t oe = hipOccupancyMaxActiveBlocksPerMultiprocessor(&maxb, fused, 512, 0);
  const bool coop = (oe == hipSuccess && maxb >= 2 &&
                     ws_size >= (size_t)WS_END * sizeof(float));

  if (coop) {
    int ph = 0;
    void* args[] = {(void*)&x, (void*)&w_qkv, (void*)&w_out, (void*)&b_out,
                    (void*)&ws, (void*)&y, (void*)&ph};
    hipError_t e = hipLaunchCooperativeKernel(reinterpret_cast<void*>(fused),
                                              dim3(512), dim3(512), args, 0, stream);
    if (e == hipSuccess) return;
  }
  fused<<<512, 512, 0, stream>>>(x, w_qkv, w_out, b_out, ws, y, 1);
  fused<<<128, 512, 0, stream>>>(x, w_qkv, w_out, b_out, ws, y, 2);
  fused<<< 32, 512, 0, stream>>>(x, w_qkv, w_out, b_out, ws, y, 3);
  fused<<<512, 512, 0, stream>>>(x, w_qkv, w_out, b_out, ws, y, 4);
}